// Round 5
// baseline (867.631 us; speedup 1.0000x reference)
//
#include <hip/hip_runtime.h>

#define N_PTS 131072
#define DIM   64
#define CELLS 256
#define EPSF  1e-8f

// ws layout (floats): [0..255]=||P_c||^2  [256..511]=||G_c||^2
//                     [512..767]=gate     [768]=cscale
// ---------------------------------------------------------------------------
__global__ void prep_kernel(const float* __restrict__ prototypes,
                            const float* __restrict__ grid_pos,
                            const float* __restrict__ gate_logits,
                            const float* __restrict__ temp_raw,
                            float* __restrict__ ws) {
    const int c = threadIdx.x;  // 256 threads, 1 block
    const float* p = prototypes + c * DIM;
    const float* g = grid_pos   + c * DIM;
    float pn = 0.f, gn = 0.f;
#pragma unroll
    for (int k = 0; k < DIM; ++k) {
        pn = fmaf(p[k], p[k], pn);
        gn = fmaf(g[k], g[k], gn);
    }
    ws[c]             = pn;
    ws[CELLS + c]     = gn;
    ws[2 * CELLS + c] = 1.f / (1.f + expf(-gate_logits[c]));
    if (c == 0) {
        float sg   = 1.f / (1.f + expf(-temp_raw[0]));
        float temp = sg * (1.f - 0.001f) + 0.001f;
        ws[3 * CELLS] = -1.4426950408889634f / temp;  // -log2(e)/temp
    }
}

// ---- dot helpers over 16 named float4s --------------------------------------
#define D4(xa, b, row, A_) \
    A_##0 = fmaf(xa.x, row[b + 0], A_##0); \
    A_##1 = fmaf(xa.y, row[b + 1], A_##1); \
    A_##2 = fmaf(xa.z, row[b + 2], A_##2); \
    A_##3 = fmaf(xa.w, row[b + 3], A_##3);

#define DOT64(row, A_) \
    D4(x0, 0, row, A_)  D4(x1, 4, row, A_)  D4(x2, 8, row, A_)  D4(x3, 12, row, A_) \
    D4(x4, 16, row, A_) D4(x5, 20, row, A_) D4(x6, 24, row, A_) D4(x7, 28, row, A_) \
    D4(x8, 32, row, A_) D4(x9, 36, row, A_) D4(x10, 40, row, A_) D4(x11, 44, row, A_) \
    D4(x12, 48, row, A_) D4(x13, 52, row, A_) D4(x14, 56, row, A_) D4(x15, 60, row, A_)

#define XN4(xa) \
    xn0 = fmaf(xa.x, xa.x, xn0); xn1 = fmaf(xa.y, xa.y, xn1); \
    xn2 = fmaf(xa.z, xa.z, xn2); xn3 = fmaf(xa.w, xa.w, xn3);

// blended accumulation: bN.{xyzw} += t * pr[...], pr is SGPR-resident
#define BLD4(B_, k, pr, t) \
    B_.x = fmaf(t, pr[k + 0], B_.x); B_.y = fmaf(t, pr[k + 1], B_.y); \
    B_.z = fmaf(t, pr[k + 2], B_.z); B_.w = fmaf(t, pr[k + 3], B_.w);

#define BLEND64(pr, t) \
    BLD4(b0, 0, pr, t)  BLD4(b1, 4, pr, t)  BLD4(b2, 8, pr, t)  BLD4(b3, 12, pr, t) \
    BLD4(b4, 16, pr, t) BLD4(b5, 20, pr, t) BLD4(b6, 24, pr, t) BLD4(b7, 28, pr, t) \
    BLD4(b8, 32, pr, t) BLD4(b9, 36, pr, t) BLD4(b10, 40, pr, t) BLD4(b11, 44, pr, t) \
    BLD4(b12, 48, pr, t) BLD4(b13, 52, pr, t) BLD4(b14, 56, pr, t) BLD4(b15, 60, pr, t)

// Route a loaded value through an opaque asm def: the RA can no longer
// rematerialize it by re-issuing the (invariant) load -> stays in VGPRs.
#define PIN4(a) asm volatile("" : "+v"(a.x), "+v"(a.y), "+v"(a.z), "+v"(a.w));

// ---------------------------------------------------------------------------
// Fused kernel: thread <-> point. x row pinned in 64 VGPRs; P/G rows stream
// through SGPRs (wave-uniform s_load); blended accumulated in 64 more VGPRs
// (FMA-defined -> not rematerializable). One pass over cells does dots, exp,
// unscaled-w store, and blend. Epilogue: alpha, blended store, L2-hot w
// rescale of the thread's own row.
// ---------------------------------------------------------------------------
__global__ __launch_bounds__(256, 2)
void som_kernel(const float* __restrict__ x,
                const float* __restrict__ P,
                const float* __restrict__ G,
                const float* __restrict__ ws,
                float* __restrict__ out) {
    const int i = blockIdx.x * 256 + threadIdx.x;

    const float4* xp = reinterpret_cast<const float4*>(x) + (size_t)i * 16;
    float4 x0 = xp[0],  x1 = xp[1],  x2 = xp[2],  x3 = xp[3];
    float4 x4 = xp[4],  x5 = xp[5],  x6 = xp[6],  x7 = xp[7];
    float4 x8 = xp[8],  x9 = xp[9],  x10 = xp[10], x11 = xp[11];
    float4 x12 = xp[12], x13 = xp[13], x14 = xp[14], x15 = xp[15];

    float xn0 = 0.f, xn1 = 0.f, xn2 = 0.f, xn3 = 0.f;
    XN4(x0) XN4(x1) XN4(x2) XN4(x3) XN4(x4) XN4(x5) XN4(x6) XN4(x7)
    XN4(x8) XN4(x9) XN4(x10) XN4(x11) XN4(x12) XN4(x13) XN4(x14) XN4(x15)
    const float xn = (xn0 + xn1) + (xn2 + xn3);

    PIN4(x0)  PIN4(x1)  PIN4(x2)  PIN4(x3)
    PIN4(x4)  PIN4(x5)  PIN4(x6)  PIN4(x7)
    PIN4(x8)  PIN4(x9)  PIN4(x10) PIN4(x11)
    PIN4(x12) PIN4(x13) PIN4(x14) PIN4(x15)

    const float cscale = ws[3 * CELLS];
    float s1 = 0.f, sg = 0.f;

    float4 b0 = {0,0,0,0}, b1 = {0,0,0,0}, b2 = {0,0,0,0}, b3 = {0,0,0,0};
    float4 b4 = {0,0,0,0}, b5 = {0,0,0,0}, b6 = {0,0,0,0}, b7 = {0,0,0,0};
    float4 b8 = {0,0,0,0}, b9 = {0,0,0,0}, b10 = {0,0,0,0}, b11 = {0,0,0,0};
    float4 b12 = {0,0,0,0}, b13 = {0,0,0,0}, b14 = {0,0,0,0}, b15 = {0,0,0,0};

    float* wrow = out + (size_t)N_PTS * DIM + (size_t)i * CELLS;

#define CELL(cc, tvar) { \
    const int c = c0 + cc; \
    const float* __restrict__ pr = P + c * DIM; \
    float pa0 = 0.f, pa1 = 0.f, pa2 = 0.f, pa3 = 0.f; \
    DOT64(pr, pa) \
    const float* __restrict__ gr = G + c * DIM; \
    float ga0 = 0.f, ga1 = 0.f, ga2 = 0.f, ga3 = 0.f; \
    DOT64(gr, ga) \
    float dotp = (pa0 + pa1) + (pa2 + pa3); \
    float dotg = (ga0 + ga1) + (ga2 + ga3); \
    float dp2 = fmaf(-2.f, dotp, xn + ws[c]); \
    float dg2 = fmaf(-2.f, dotg, xn + ws[CELLS + c]); \
    float dtot = sqrtf(fmaxf(dp2, 0.f)) + sqrtf(fmaxf(dg2, 0.f)); \
    float e = exp2f(dtot * cscale); \
    s1 += e; \
    tvar = e * ws[2 * CELLS + c]; \
    sg += tvar; \
    BLEND64(pr, tvar) }

#pragma unroll 1
    for (int c0 = 0; c0 < CELLS; c0 += 4) {
        float t0, t1, t2, t3;
        CELL(0, t0) CELL(1, t1) CELL(2, t2) CELL(3, t3)
        *reinterpret_cast<float4*>(wrow + c0) = make_float4(t0, t1, t2, t3);
    }
#undef CELL

    // ref: w1=e/(s1+eps); t1=w1*gate; s2=sum t1; w2=t1/(s2+eps)
    //   => w2 = (e*gate)*alpha,  alpha = 1/((s1+eps)*(s2+eps)),
    //      blended = (t @ P) * alpha
    const float A     = s1 + EPSF;
    const float s2    = sg / A;
    const float alpha = 1.f / (A * (s2 + EPSF));

    // blended row
    float4* brow = reinterpret_cast<float4*>(out + (size_t)i * DIM);
#define BST(j, B_) brow[j] = make_float4(B_.x * alpha, B_.y * alpha, \
                                         B_.z * alpha, B_.w * alpha);
    BST(0, b0)   BST(1, b1)   BST(2, b2)   BST(3, b3)
    BST(4, b4)   BST(5, b5)   BST(6, b6)   BST(7, b7)
    BST(8, b8)   BST(9, b9)   BST(10, b10) BST(11, b11)
    BST(12, b12) BST(13, b13) BST(14, b14) BST(15, b15)
#undef BST

    // rescale own w row (L2-hot: this thread just wrote it)
#pragma unroll 4
    for (int j = 0; j < CELLS; j += 4) {
        float4 v = *reinterpret_cast<float4*>(wrow + j);
        v.x *= alpha; v.y *= alpha; v.z *= alpha; v.w *= alpha;
        *reinterpret_cast<float4*>(wrow + j) = v;
    }
}

extern "C" void kernel_launch(void* const* d_in, const int* in_sizes, int n_in,
                              void* d_out, int out_size, void* d_ws, size_t ws_size,
                              hipStream_t stream) {
    const float* x           = (const float*)d_in[0];
    const float* prototypes  = (const float*)d_in[1];
    const float* grid_pos    = (const float*)d_in[2];
    const float* gate_logits = (const float*)d_in[3];
    const float* temp_raw    = (const float*)d_in[4];
    float*       out         = (float*)d_out;
    float*       ws          = (float*)d_ws;

    prep_kernel<<<1, CELLS, 0, stream>>>(prototypes, grid_pos, gate_logits,
                                         temp_raw, ws);
    som_kernel<<<N_PTS / 256, 256, 0, stream>>>(x, prototypes, grid_pos, ws, out);
}

// Round 6
// 453.319 us; speedup vs baseline: 1.9140x; 1.9140x over previous
//
#include <hip/hip_runtime.h>

#define N_PTS 131072
#define DIM   64
#define CELLS 256
#define EPSF  1e-8f
#define KP    68          // padded LDS row stride (dwords); stride-68 + XOR swizzle -> <=2-way banks
#define WS_ALPHA 1024     // alpha array offset (floats) in d_ws

// ---------------------------------------------------------------------------
// prep: per-cell norms, gate=sigmoid(gate_logits), cscale=-log2(e)/temp
// ws: [0..255]=||P||^2 [256..511]=||G||^2 [512..767]=gate [768]=cscale
// ---------------------------------------------------------------------------
__global__ void prep_kernel(const float* __restrict__ prototypes,
                            const float* __restrict__ grid_pos,
                            const float* __restrict__ gate_logits,
                            const float* __restrict__ temp_raw,
                            float* __restrict__ ws) {
    const int c = threadIdx.x;  // 256 threads, 1 block
    const float* p = prototypes + c * DIM;
    const float* g = grid_pos   + c * DIM;
    float pn = 0.f, gn = 0.f;
#pragma unroll
    for (int k = 0; k < DIM; ++k) {
        pn = fmaf(p[k], p[k], pn);
        gn = fmaf(g[k], g[k], gn);
    }
    ws[c]             = pn;
    ws[CELLS + c]     = gn;
    ws[2 * CELLS + c] = 1.f / (1.f + expf(-gate_logits[c]));
    if (c == 0) {
        float sg   = 1.f / (1.f + expf(-temp_raw[0]));
        float temp = sg * (1.f - 0.001f) + 0.001f;
        ws[3 * CELLS] = -1.4426950408889634f / temp;  // -log2(e)/temp
    }
}

// ---------------------------------------------------------------------------
// dist: tiled rank-1-update GEMM. Block tile: 64 pts x 64-cell chunk (x4).
// k-major LDS with XOR swizzle: elem(k, idx) at [k*KP + (idx ^ (4*(k&15)))].
// Thread (pr=t&15, cr=t>>4): pts 4pr..+3, cells 4cr..+3; 32 accums.
// Outputs: unscaled t = e*gate to w_out (coalesced via LDS re-stage),
//          alpha per point to alpha_out.
// ---------------------------------------------------------------------------
__global__ __launch_bounds__(256, 3)
void dist_kernel(const float* __restrict__ x,
                 const float* __restrict__ P,
                 const float* __restrict__ G,
                 const float* __restrict__ ws,
                 float* __restrict__ w_out,
                 float* __restrict__ alpha_out) {
    __shared__ __align__(16) float xT[64 * KP];
    __shared__ __align__(16) float PT[64 * KP];   // reused as t-tile post-k-loop
    __shared__ __align__(16) float GT[64 * KP];   // reused as reduction buf
    __shared__ float xn[64];
    float* red = GT;                               // [2][64][17] overlay

    const int t  = threadIdx.x;
    const int pr = t & 15;
    const int cr = t >> 4;
    const int pbase = blockIdx.x * 64;

    // ---- stage xT (transpose + swizzle) and ||x||^2 partials ----
    const float4* x4 = reinterpret_cast<const float4*>(x);
#pragma unroll
    for (int j = 0; j < 4; ++j) {
        int f  = j * 256 + t;
        int pt = f >> 4;           // 0..63 (wave-uniform per 16 lanes)
        int q  = f & 15;
        float4 v = x4[(size_t)(pbase + pt) * 16 + q];
#pragma unroll
        for (int jj = 0; jj < 4; ++jj) {
            int k = 4 * q + jj;
            xT[k * KP + (pt ^ (4 * (k & 15)))] = (&v.x)[jj];
        }
        red[pt * 17 + q] = v.x*v.x + v.y*v.y + v.z*v.z + v.w*v.w;
    }
    __syncthreads();
    if (t < 64) {
        float a = 0.f;
#pragma unroll
        for (int m = 0; m < 16; ++m) a += red[t * 17 + m];
        xn[t] = a;
    }
    __syncthreads();

    const float cscale = ws[3 * CELLS];
    float s1r = 0.f, sgr = 0.f;    // meaningful for t<64 (point t)

    const float4* P4 = reinterpret_cast<const float4*>(P);
    const float4* G4 = reinterpret_cast<const float4*>(G);

#pragma unroll 1
    for (int cc = 0; cc < 4; ++cc) {
        const int cc0 = cc * 64;
        // ---- stage P/G chunk (transpose + swizzle) ----
#pragma unroll
        for (int j = 0; j < 4; ++j) {
            int f  = j * 256 + t;
            int cl = f >> 4;
            int q  = f & 15;
            float4 v = P4[(size_t)(cc0 + cl) * 16 + q];
            float4 u = G4[(size_t)(cc0 + cl) * 16 + q];
#pragma unroll
            for (int jj = 0; jj < 4; ++jj) {
                int k = 4 * q + jj;
                int col = cl ^ (4 * (k & 15));
                PT[k * KP + col] = (&v.x)[jj];
                GT[k * KP + col] = (&u.x)[jj];
            }
        }
        __syncthreads();

        float accP[4][4], accG[4][4];
#pragma unroll
        for (int i = 0; i < 4; ++i)
#pragma unroll
            for (int j = 0; j < 4; ++j) { accP[i][j] = 0.f; accG[i][j] = 0.f; }

#pragma unroll 16
        for (int k = 0; k < 64; ++k) {
            const int s = 4 * (k & 15);
            const float4 xf = *reinterpret_cast<const float4*>(&xT[k*KP + ((4*pr) ^ s)]);
            const float4 pf = *reinterpret_cast<const float4*>(&PT[k*KP + ((4*cr) ^ s)]);
            const float4 gf = *reinterpret_cast<const float4*>(&GT[k*KP + ((4*cr) ^ s)]);
#pragma unroll
            for (int i = 0; i < 4; ++i) {
                const float xv = (&xf.x)[i];
                accP[i][0] = fmaf(xv, pf.x, accP[i][0]);
                accP[i][1] = fmaf(xv, pf.y, accP[i][1]);
                accP[i][2] = fmaf(xv, pf.z, accP[i][2]);
                accP[i][3] = fmaf(xv, pf.w, accP[i][3]);
                accG[i][0] = fmaf(xv, gf.x, accG[i][0]);
                accG[i][1] = fmaf(xv, gf.y, accG[i][1]);
                accG[i][2] = fmaf(xv, gf.z, accG[i][2]);
                accG[i][3] = fmaf(xv, gf.w, accG[i][3]);
            }
        }
        __syncthreads();   // all waves done reading xT/PT/GT this chunk

        // ---- epilogue: t = exp(-(dP+dG)/temp)*gate (registers only) ----
        const float4 pnv = *reinterpret_cast<const float4*>(ws + cc0 + 4*cr);
        const float4 gnv = *reinterpret_cast<const float4*>(ws + CELLS + cc0 + 4*cr);
        const float4 gav = *reinterpret_cast<const float4*>(ws + 2*CELLS + cc0 + 4*cr);
        float tt[4][4], s1p[4], sgp[4];
#pragma unroll
        for (int i = 0; i < 4; ++i) {
            const float xnv = xn[4*pr + i];
            s1p[i] = 0.f; sgp[i] = 0.f;
#pragma unroll
            for (int j = 0; j < 4; ++j) {
                float dp2 = fmaf(-2.f, accP[i][j], xnv + (&pnv.x)[j]);
                float dg2 = fmaf(-2.f, accG[i][j], xnv + (&gnv.x)[j]);
                float d   = sqrtf(fmaxf(dp2, 0.f)) + sqrtf(fmaxf(dg2, 0.f));
                float e   = exp2f(d * cscale);
                s1p[i] += e;
                float tv = e * (&gav.x)[j];
                sgp[i] += tv;
                tt[i][j] = tv;
            }
        }
        // ---- stage t into dead PT buffer; partials into red (dead GT) ----
        float* ttile = PT;
#pragma unroll
        for (int i = 0; i < 4; ++i) {
            int row = 4*pr + i;
            *reinterpret_cast<float4*>(&ttile[row*KP + ((4*cr) ^ (4*(row & 15)))]) =
                make_float4(tt[i][0], tt[i][1], tt[i][2], tt[i][3]);
            red[row*17 + cr]        = s1p[i];
            red[1088 + row*17 + cr] = sgp[i];
        }
        __syncthreads();   // ttile + red ready

        // ---- coalesced unscaled-t store + s1/sg accumulation ----
#pragma unroll
        for (int j = 0; j < 4; ++j) {
            int f   = j * 256 + t;
            int row = f >> 4;
            int q   = f & 15;
            float4 v = *reinterpret_cast<const float4*>(
                &ttile[row*KP + ((4*q) ^ (4*(row & 15)))]);
            *reinterpret_cast<float4*>(
                w_out + (size_t)(pbase + row) * CELLS + cc0 + 4*q) = v;
        }
        if (t < 64) {
            float a = 0.f, b = 0.f;
#pragma unroll
            for (int m = 0; m < 16; ++m) {
                a += red[t*17 + m];
                b += red[1088 + t*17 + m];
            }
            s1r += a; sgr += b;
        }
        __syncthreads();   // before PT/GT restage
    }

    // ref: w1=e/(s1+eps); t1=w1*gate; s2=sum t1; w2=t1/(s2+eps)
    //   => w2 = (e*gate)*alpha, alpha = 1/((s1+eps)*(s2+eps))
    if (t < 64) {
        const float A  = s1r + EPSF;
        const float s2 = sgr / A;
        alpha_out[pbase + t] = 1.f / (A * (s2 + EPSF));
    }
}

// ---------------------------------------------------------------------------
// blend: w2 = t*alpha (write-back) and blended = w2 @ P. Same tiling skeleton.
// wT k-major (cell-major) swizzled; P staged row-major (already k-major).
// Thread (pr=t&15 -> 4 pts, dr=t>>4 -> 4 dims); 16 accums.
// ---------------------------------------------------------------------------
__global__ __launch_bounds__(256, 4)
void blend_kernel(float* __restrict__ w,          // in: unscaled t, out: w2
                  const float* __restrict__ P,
                  const float* __restrict__ alpha_in,
                  float* __restrict__ bl) {
    __shared__ __align__(16) float wT[64 * KP];
    __shared__ __align__(16) float Pt[64 * KP];
    __shared__ float als[64];

    const int t  = threadIdx.x;
    const int pr = t & 15;
    const int dr = t >> 4;
    const int pbase = blockIdx.x * 64;

    if (t < 64) als[t] = alpha_in[pbase + t];

    float acc[4][4];
#pragma unroll
    for (int i = 0; i < 4; ++i)
#pragma unroll
        for (int j = 0; j < 4; ++j) acc[i][j] = 0.f;

    const float4* P4 = reinterpret_cast<const float4*>(P);
    __syncthreads();   // als ready

#pragma unroll 1
    for (int cc = 0; cc < 4; ++cc) {
        const int cc0 = cc * 64;
        // ---- stage w chunk: scale by alpha, write back w2, transpose to LDS
#pragma unroll
        for (int j = 0; j < 4; ++j) {
            int f  = j * 256 + t;
            int pt = f >> 4;
            int q  = f & 15;
            float* gp = w + (size_t)(pbase + pt) * CELLS + cc0 + 4*q;
            float4 v = *reinterpret_cast<const float4*>(gp);
            const float al = als[pt];
            v.x *= al; v.y *= al; v.z *= al; v.w *= al;
            *reinterpret_cast<float4*>(gp) = v;     // final w2, coalesced
#pragma unroll
            for (int jj = 0; jj < 4; ++jj) {
                int k = 4*q + jj;
                wT[k * KP + (pt ^ (4 * (k & 15)))] = (&v.x)[jj];
            }
        }
        // ---- stage P chunk row-major (b128 straight through) ----
#pragma unroll
        for (int j = 0; j < 4; ++j) {
            int f  = j * 256 + t;
            int cl = f >> 4;
            int q  = f & 15;
            float4 v = P4[(size_t)(cc0 + cl) * 16 + q];
            *reinterpret_cast<float4*>(&Pt[cl * KP + 4*q]) = v;
        }
        __syncthreads();

#pragma unroll 16
        for (int k = 0; k < 64; ++k) {
            const int s = 4 * (k & 15);
            const float4 wf = *reinterpret_cast<const float4*>(&wT[k*KP + ((4*pr) ^ s)]);
            const float4 pf = *reinterpret_cast<const float4*>(&Pt[k*KP + 4*dr]);
#pragma unroll
            for (int i = 0; i < 4; ++i) {
                const float wv = (&wf.x)[i];
                acc[i][0] = fmaf(wv, pf.x, acc[i][0]);
                acc[i][1] = fmaf(wv, pf.y, acc[i][1]);
                acc[i][2] = fmaf(wv, pf.z, acc[i][2]);
                acc[i][3] = fmaf(wv, pf.w, acc[i][3]);
            }
        }
        __syncthreads();   // before restage
    }

    // ---- blended store: 16 lanes cover a full 256B row -> coalesced ----
#pragma unroll
    for (int i = 0; i < 4; ++i) {
        *reinterpret_cast<float4*>(
            bl + (size_t)(pbase + 4*pr + i) * DIM + 4*dr) =
            make_float4(acc[i][0], acc[i][1], acc[i][2], acc[i][3]);
    }
}

extern "C" void kernel_launch(void* const* d_in, const int* in_sizes, int n_in,
                              void* d_out, int out_size, void* d_ws, size_t ws_size,
                              hipStream_t stream) {
    const float* x           = (const float*)d_in[0];
    const float* prototypes  = (const float*)d_in[1];
    const float* grid_pos    = (const float*)d_in[2];
    const float* gate_logits = (const float*)d_in[3];
    const float* temp_raw    = (const float*)d_in[4];
    float*       out         = (float*)d_out;
    float*       blended     = out;                           // [N, 64]
    float*       w           = out + (size_t)N_PTS * DIM;     // [N, 256]
    float*       ws          = (float*)d_ws;
    float*       alpha       = ws + WS_ALPHA;                 // N floats

    prep_kernel<<<1, CELLS, 0, stream>>>(prototypes, grid_pos, gate_logits,
                                         temp_raw, ws);
    dist_kernel<<<N_PTS / 64, 256, 0, stream>>>(x, prototypes, grid_pos, ws,
                                                w, alpha);
    blend_kernel<<<N_PTS / 64, 256, 0, stream>>>(w, prototypes, alpha, blended);
}

// Round 7
// 413.072 us; speedup vs baseline: 2.1004x; 1.0974x over previous
//
#include <hip/hip_runtime.h>

#define N_PTS 131072
#define DIM   64
#define CELLS 256
#define EPSF  1e-8f
#define WS_ALPHA 1024   // alpha array offset (floats) in d_ws

// ---------------------------------------------------------------------------
// prep: per-cell norms, gate=sigmoid(gate_logits), cscale=-log2(e)/temp
// ws: [0..255]=||P||^2 [256..511]=||G||^2 [512..767]=gate [768]=cscale
// ---------------------------------------------------------------------------
__global__ void prep_kernel(const float* __restrict__ prototypes,
                            const float* __restrict__ grid_pos,
                            const float* __restrict__ gate_logits,
                            const float* __restrict__ temp_raw,
                            float* __restrict__ ws) {
    const int c = threadIdx.x;
    const float* p = prototypes + c * DIM;
    const float* g = grid_pos   + c * DIM;
    float pn = 0.f, gn = 0.f;
#pragma unroll
    for (int k = 0; k < DIM; ++k) {
        pn = fmaf(p[k], p[k], pn);
        gn = fmaf(g[k], g[k], gn);
    }
    ws[c]             = pn;
    ws[CELLS + c]     = gn;
    ws[2 * CELLS + c] = 1.f / (1.f + expf(-gate_logits[c]));
    if (c == 0) {
        float sg   = 1.f / (1.f + expf(-temp_raw[0]));
        float temp = sg * (1.f - 0.001f) + 0.001f;
        ws[3 * CELLS] = -1.4426950408889634f / temp;  // -log2(e)/temp
    }
}

// ---------------------------------------------------------------------------
// dist: tiled rank-1 GEMM, tile 128 pts x 64-cell chunks (x4), thread =
// 8 pts x 4 cells (64 accums). LDS swizzle: elem(k,idx) at
// [k*STR + 4*((idx>>2)^sigma(k)) + (idx&3)]; staging maps LANE -> contiguous
// column => wave-uniform row + lane-consecutive col = conflict-free writes.
// k-loop: x-frags broadcast (16 lanes), P/G-frags 16-distinct-block b128.
// LDS: xT[64][128] | PT[64][64] | GT[64][64] = 64KB dynamic exactly.
// ttile (unscaled t, for coalesced w store) overlays PT+GT = [128][64].
// ---------------------------------------------------------------------------
__global__ __launch_bounds__(256, 2)
void dist_kernel(const float* __restrict__ x,
                 const float* __restrict__ P,
                 const float* __restrict__ G,
                 const float* __restrict__ ws,
                 float* __restrict__ w_out,
                 float* __restrict__ alpha_out) {
    extern __shared__ float lds[];
    float* xT = lds;            // [64][128]  (8192 floats)
    float* PT = lds + 8192;     // [64][64]   (4096)
    float* GT = lds + 12288;    // [64][64]   (4096)

    const int t  = threadIdx.x;
    const int pr = t >> 4;      // 0..15: pts {4pr+i} and {64+4pr+i}
    const int cr = t & 15;      // 0..15: cells 4cr..4cr+3 (within chunk)
    const int pbase = blockIdx.x * 128;

    // ---- stage xT (lane->pt contiguous; rows k wave-uniform) ----
    {
        const int pt = t & 127;
        const int qh = t >> 7;                 // 0..1 (k-half)
        const float4* xp = reinterpret_cast<const float4*>(
            x + (size_t)(pbase + pt) * DIM);
        float xpart = 0.f;
#pragma unroll
        for (int j = 0; j < 8; ++j) {
            const int q = qh * 8 + j;          // thread-contiguous 128B stream
            float4 v = xp[q];
            xpart += v.x*v.x + v.y*v.y + v.z*v.z + v.w*v.w;
#pragma unroll
            for (int jj = 0; jj < 4; ++jj) {
                const int k = 4 * q + jj;
                xT[k * 128 + 4 * ((pt >> 2) ^ (k >> 1)) + (pt & 3)] = (&v.x)[jj];
            }
        }
        PT[qh * 128 + pt] = xpart;             // scratch (PT not staged yet)
    }
    __syncthreads();
    // gather ||x||^2 for this thread's 8 pts (broadcast reads)
    float xn[8];
#pragma unroll
    for (int i = 0; i < 8; ++i) {
        const int p = ((i < 4) ? 0 : 64) + 4 * pr + (i & 3);
        xn[i] = PT[p] + PT[128 + p];
    }
    __syncthreads();

    const float cscale = ws[3 * CELLS];
    float s1r[8], sgr[8];
#pragma unroll
    for (int i = 0; i < 8; ++i) { s1r[i] = 0.f; sgr[i] = 0.f; }

#pragma unroll 1
    for (int cc = 0; cc < 4; ++cc) {
        const int cc0 = cc * 64;
        // ---- stage PT/GT (lane->cell contiguous; rows k wave-uniform) ----
        {
            const int cl = t & 63;
            const int qb = t >> 6;             // 0..3
            const float4* P4 = reinterpret_cast<const float4*>(
                P + (size_t)(cc0 + cl) * DIM);
            const float4* G4 = reinterpret_cast<const float4*>(
                G + (size_t)(cc0 + cl) * DIM);
#pragma unroll
            for (int j = 0; j < 4; ++j) {
                const int q = 4 * qb + j;      // thread-contiguous 64B stream
                float4 v = P4[q];
                float4 u = G4[q];
#pragma unroll
                for (int jj = 0; jj < 4; ++jj) {
                    const int k   = 4 * q + jj;
                    const int off = k * 64 + 4 * ((cl >> 2) ^ (k & 15)) + (cl & 3);
                    PT[off] = (&v.x)[jj];
                    GT[off] = (&u.x)[jj];
                }
            }
        }
        __syncthreads();

        float accP[8][4], accG[8][4];
#pragma unroll
        for (int i = 0; i < 8; ++i)
#pragma unroll
            for (int j = 0; j < 4; ++j) { accP[i][j] = 0.f; accG[i][j] = 0.f; }

#pragma unroll 8
        for (int k = 0; k < 64; ++k) {
            const float4 xf0 = *reinterpret_cast<const float4*>(
                &xT[k * 128 + 4 * (pr ^ (k >> 1))]);
            const float4 xf1 = *reinterpret_cast<const float4*>(
                &xT[k * 128 + 4 * ((pr + 16) ^ (k >> 1))]);
            const float4 pf = *reinterpret_cast<const float4*>(
                &PT[k * 64 + 4 * (cr ^ (k & 15))]);
            const float4 gf = *reinterpret_cast<const float4*>(
                &GT[k * 64 + 4 * (cr ^ (k & 15))]);
#pragma unroll
            for (int i = 0; i < 4; ++i) {
                const float a = (&xf0.x)[i];
                const float b = (&xf1.x)[i];
#pragma unroll
                for (int j = 0; j < 4; ++j) {
                    const float pv = (&pf.x)[j];
                    const float gv = (&gf.x)[j];
                    accP[i][j]     = fmaf(a, pv, accP[i][j]);
                    accG[i][j]     = fmaf(a, gv, accG[i][j]);
                    accP[4 + i][j] = fmaf(b, pv, accP[4 + i][j]);
                    accG[4 + i][j] = fmaf(b, gv, accG[4 + i][j]);
                }
            }
        }
        __syncthreads();   // PT/GT dead -> reuse as ttile [128][64]

        // ---- epilogue: t = exp(-(dP+dG)/temp)*gate; shuffle-reduce s1/sg ---
        const float4 pnv = *reinterpret_cast<const float4*>(ws + cc0 + 4 * cr);
        const float4 gnv = *reinterpret_cast<const float4*>(ws + CELLS + cc0 + 4 * cr);
        const float4 gav = *reinterpret_cast<const float4*>(ws + 2 * CELLS + cc0 + 4 * cr);
        float* ttile = PT;   // [128][64] spans PT+GT
#pragma unroll
        for (int i = 0; i < 8; ++i) {
            const int p = ((i < 4) ? 0 : 64) + 4 * pr + (i & 3);
            float s1p = 0.f, sgp = 0.f;
            float tt[4];
#pragma unroll
            for (int j = 0; j < 4; ++j) {
                float dp2 = fmaf(-2.f, accP[i][j], xn[i] + (&pnv.x)[j]);
                float dg2 = fmaf(-2.f, accG[i][j], xn[i] + (&gnv.x)[j]);
                float d   = sqrtf(fmaxf(dp2, 0.f)) + sqrtf(fmaxf(dg2, 0.f));
                float e   = exp2f(d * cscale);
                s1p += e;
                float tv = e * (&gav.x)[j];
                sgp += tv;
                tt[j] = tv;
            }
            *reinterpret_cast<float4*>(&ttile[p * 64 + 4 * (cr ^ (p & 15))]) =
                make_float4(tt[0], tt[1], tt[2], tt[3]);
            // reduce over the 16-lane cell group (cr = lane&15)
            s1p += __shfl_xor(s1p, 1);  sgp += __shfl_xor(sgp, 1);
            s1p += __shfl_xor(s1p, 2);  sgp += __shfl_xor(sgp, 2);
            s1p += __shfl_xor(s1p, 4);  sgp += __shfl_xor(sgp, 4);
            s1p += __shfl_xor(s1p, 8);  sgp += __shfl_xor(sgp, 8);
            s1r[i] += s1p;
            sgr[i] += sgp;
        }
        __syncthreads();   // ttile ready

        // ---- coalesced unscaled-t store ----
#pragma unroll
        for (int j = 0; j < 8; ++j) {
            const int f   = j * 256 + t;
            const int row = f >> 4;
            const int q2  = f & 15;
            float4 v = *reinterpret_cast<const float4*>(
                &ttile[row * 64 + 4 * (q2 ^ (row & 15))]);
            *reinterpret_cast<float4*>(
                w_out + (size_t)(pbase + row) * CELLS + cc0 + 4 * q2) = v;
        }
        __syncthreads();   // before PT/GT restage
    }

    // ref: w1=e/(s1+eps); t1=w1*gate; s2=sum t1; w2=t1/(s2+eps)
    //   => w2 = (e*gate)*alpha, alpha = 1/((s1+eps)*(s2+eps))
    if (cr == 0) {
#pragma unroll
        for (int i = 0; i < 8; ++i) {
            const int p = ((i < 4) ? 0 : 64) + 4 * pr + (i & 3);
            const float A  = s1r[i] + EPSF;
            const float s2 = sgr[i] / A;
            alpha_out[pbase + p] = 1.f / (A * (s2 + EPSF));
        }
    }
}

// ---------------------------------------------------------------------------
// blend: w2 = t*alpha (write-back, folded at stage time) and blended = w2 @ P.
// Tile 256 pts x 64 dims, k = cells in 8 chunks of 32; thread = 8 pts x 8 dims
// (64 accums, ratio 4 dwords->FMA). wT[32][256] swizzled; Pt[32][64] swizzled.
// ---------------------------------------------------------------------------
__global__ __launch_bounds__(256, 2)
void blend_kernel(float* __restrict__ w,          // in: t, out: w2 = t*alpha
                  const float* __restrict__ P,
                  const float* __restrict__ alpha_in,
                  float* __restrict__ bl) {
    extern __shared__ float lds2[];
    float* wT = lds2;           // [32][256] (8192 floats)
    float* Pt = lds2 + 8192;    // [32][64]  (2048 floats)

    const int t  = threadIdx.x;
    const int pr = t & 31;      // pts {4pr+i} and {128+4pr+i}
    const int dr = t >> 5;      // dims 8dr..8dr+7
    const size_t pbase = (size_t)blockIdx.x * 256;

    const float al = alpha_in[pbase + t];   // this thread's staging row

    float acc[8][8];
#pragma unroll
    for (int i = 0; i < 8; ++i)
#pragma unroll
        for (int j = 0; j < 8; ++j) acc[i][j] = 0.f;

#pragma unroll 1
    for (int cc = 0; cc < 8; ++cc) {
        const int cc0 = cc * 32;
        // ---- stage w chunk: scale, write back w2, transpose into wT ----
        {
            float* wrow = w + (pbase + t) * CELLS + cc0;
#pragma unroll
            for (int j = 0; j < 8; ++j) {
                float4 v = *reinterpret_cast<const float4*>(wrow + 4 * j);
                v.x *= al; v.y *= al; v.z *= al; v.w *= al;
                *reinterpret_cast<float4*>(wrow + 4 * j) = v;   // final w2
#pragma unroll
                for (int jj = 0; jj < 4; ++jj) {
                    const int r = 4 * j + jj;   // cell-in-chunk (wave-uniform)
                    wT[r * 256 + 4 * ((t >> 2) ^ r) + (t & 3)] = (&v.x)[jj];
                }
            }
        }
        // ---- stage P chunk [cell][dim], dim-block swizzled by cell ----
#pragma unroll
        for (int j = 0; j < 2; ++j) {
            const int f  = j * 256 + t;
            const int cl = f & 31;
            const int q  = (f >> 5) & 15;
            float4 v = *reinterpret_cast<const float4*>(
                P + (size_t)(cc0 + cl) * DIM + 4 * q);
            *reinterpret_cast<float4*>(&Pt[cl * 64 + 4 * (q ^ (cl & 15))]) = v;
        }
        __syncthreads();

#pragma unroll 4
        for (int k = 0; k < 32; ++k) {
            const float4 wf0 = *reinterpret_cast<const float4*>(
                &wT[k * 256 + 4 * (pr ^ k)]);
            const float4 wf1 = *reinterpret_cast<const float4*>(
                &wT[k * 256 + 4 * ((32 + pr) ^ k)]);
            const float4 pf0 = *reinterpret_cast<const float4*>(
                &Pt[k * 64 + 4 * ((2 * dr) ^ (k & 15))]);
            const float4 pf1 = *reinterpret_cast<const float4*>(
                &Pt[k * 64 + 4 * ((2 * dr + 1) ^ (k & 15))]);
#pragma unroll
            for (int i = 0; i < 4; ++i) {
                const float a = (&wf0.x)[i];
                const float b = (&wf1.x)[i];
#pragma unroll
                for (int j = 0; j < 4; ++j) {
                    const float p0 = (&pf0.x)[j];
                    const float p1 = (&pf1.x)[j];
                    acc[i][j]         = fmaf(a, p0, acc[i][j]);
                    acc[i][4 + j]     = fmaf(a, p1, acc[i][4 + j]);
                    acc[4 + i][j]     = fmaf(b, p0, acc[4 + i][j]);
                    acc[4 + i][4 + j] = fmaf(b, p1, acc[4 + i][4 + j]);
                }
            }
        }
        __syncthreads();   // before restage
    }

    // ---- blended store: thread's 8 pts x 8 dims ----
#pragma unroll
    for (int i = 0; i < 8; ++i) {
        const int p = ((i < 4) ? 0 : 128) + 4 * pr + (i & 3);
        float* orow = bl + (pbase + p) * DIM + 8 * dr;
        *reinterpret_cast<float4*>(orow) =
            make_float4(acc[i][0], acc[i][1], acc[i][2], acc[i][3]);
        *reinterpret_cast<float4*>(orow + 4) =
            make_float4(acc[i][4], acc[i][5], acc[i][6], acc[i][7]);
    }
}

extern "C" void kernel_launch(void* const* d_in, const int* in_sizes, int n_in,
                              void* d_out, int out_size, void* d_ws, size_t ws_size,
                              hipStream_t stream) {
    const float* x           = (const float*)d_in[0];
    const float* prototypes  = (const float*)d_in[1];
    const float* grid_pos    = (const float*)d_in[2];
    const float* gate_logits = (const float*)d_in[3];
    const float* temp_raw    = (const float*)d_in[4];
    float*       out         = (float*)d_out;
    float*       blended     = out;                           // [N, 64]
    float*       w           = out + (size_t)N_PTS * DIM;     // [N, 256]
    float*       ws          = (float*)d_ws;
    float*       alpha       = ws + WS_ALPHA;                 // N floats

    // allow the full 64KB dynamic LDS for dist (no-op if already allowed)
    (void)hipFuncSetAttribute((const void*)dist_kernel,
                              hipFuncAttributeMaxDynamicSharedMemorySize, 65536);

    prep_kernel<<<1, CELLS, 0, stream>>>(prototypes, grid_pos, gate_logits,
                                         temp_raw, ws);
    dist_kernel<<<N_PTS / 128, 256, 65536, stream>>>(x, prototypes, grid_pos,
                                                     ws, w, alpha);
    blend_kernel<<<N_PTS / 256, 256, 40960, stream>>>(w, prototypes, alpha,
                                                      blended);
}